// Round 2
// baseline (463.994 us; speedup 1.0000x reference)
//
#include <hip/hip_runtime.h>
#include <stdint.h>

typedef unsigned short u16;
typedef __attribute__((ext_vector_type(8))) short short8;
typedef __attribute__((ext_vector_type(4))) float f32x4;

#define NTOK 256
#define KGU  5120
#define HCOL 27648
#define NPD  2560
#define KD   27648
#define SPLITK 16
#define KCH  1728            // 27648/16
#define PELEMS (NTOK*NPD)    // 655360

// ring pipeline geometry (shared by both GEMMs)
#define RB   5               // ring buffers
#define ABUF 16384           // A tile bytes: [256 rows][32 k] bf16
#define BBUF 8192            // B tile bytes: [64 rows][32 k] fp32
#define BUFB (ABUF + BBUF)   // 24576; 5 bufs = 120 KB LDS

__device__ __forceinline__ void gl_lds16(const void* gp, void* lp) {
  __builtin_amdgcn_global_load_lds((const __attribute__((address_space(1))) uint32_t*)gp,
                                   (__attribute__((address_space(3))) uint32_t*)lp, 16, 0, 0);
}
__device__ __forceinline__ uint32_t f2bf(float x) {  // RNE f32->bf16 bits
  uint32_t b = __float_as_uint(x);
  return (b + 0x7fffu + ((b >> 16) & 1u)) >> 16;
}
__device__ __forceinline__ uint32_t pk2(float lo, float hi) { return f2bf(lo) | (f2bf(hi) << 16); }
__device__ __forceinline__ float silu(float x) {
  return x * __builtin_amdgcn_rcpf(1.f + __expf(-x));
}
__device__ __forceinline__ short8 mk_bf8(const float4& a, const float4& b) {
  union { uint32_t u[4]; short8 s; } cv;
  cv.u[0] = pk2(a.x, a.y); cv.u[1] = pk2(a.z, a.w);
  cv.u[2] = pk2(b.x, b.y); cv.u[3] = pk2(b.z, b.w);
  return cv.s;
}

// ---------------- kernel 0: x fp32 -> bf16 ----------------
__global__ __launch_bounds__(256) void k_cvt(const float* __restrict__ X, u16* __restrict__ Xb) {
  int i = (blockIdx.x * 256 + threadIdx.x) * 8;
  float4 a = *(const float4*)(X + i);
  float4 b = *(const float4*)(X + i + 4);
  uint4 v;
  v.x = pk2(a.x, a.y); v.y = pk2(a.z, a.w); v.z = pk2(b.x, b.y); v.w = pk2(b.z, b.w);
  *(uint4*)(Xb + i) = v;
}

// tiny per-channel MLP, 4 gate + 4 up values at once
__device__ __forceinline__ void qrun4x2(
    const float* pg, const float* pu,
    const float4* __restrict__ cg0, const float* __restrict__ cg1, float b2g0, float b2g1,
    const float4* __restrict__ cu0, const float* __restrict__ cu1, float b2u0, float b2u1,
    float* hout) {
  float sg[4], cg[4], su[4], cu[4], og0[4], og1[4], ou0[4], ou1[4];
#pragma unroll
  for (int e = 0; e < 4; ++e) {
    sg[e] = __sinf(pg[e]); cg[e] = __cosf(pg[e]);
    su[e] = __sinf(pu[e]); cu[e] = __cosf(pu[e]);
    og0[e] = b2g0; og1[e] = b2g1; ou0[e] = b2u0; ou1[e] = b2u1;
  }
#pragma unroll 4
  for (int m = 0; m < 32; ++m) {
    float4 kg = cg0[m]; float kg1 = cg1[m];
    float4 ku = cu0[m]; float ku1 = cu1[m];
#pragma unroll
    for (int e = 0; e < 4; ++e) {
      float hg = fmaxf(fmaf(sg[e], kg.x, fmaf(cg[e], kg.y, kg.z)), 0.f);
      og0[e] = fmaf(hg, kg.w, og0[e]);
      og1[e] = fmaf(hg, kg1,  og1[e]);
      float hu = fmaxf(fmaf(su[e], ku.x, fmaf(cu[e], ku.y, ku.z)), 0.f);
      ou0[e] = fmaf(hu, ku.w, ou0[e]);
      ou1[e] = fmaf(hu, ku1,  ou1[e]);
    }
  }
#pragma unroll
  for (int e = 0; e < 4; ++e) {
    hout[2*e]   = silu(og0[e]) * ou0[e];
    hout[2*e+1] = silu(og1[e]) * ou1[e];
  }
}

// ---------------- kernel 1: fused gate+up GEMM + QRUN epilogue -> h bf16 ----------------
// 512 thr (8 waves: wm 0..3 x wn 0..1), tile M=256 x 32 p-cols (32 gate + 32 up W-rows)
// BK=32, ring RB=5 depth-3, counted vmcnt(9), 1 barrier/iter.
__global__ __launch_bounds__(512, 2)
void k_gateup(const u16* __restrict__ X,
              const float* __restrict__ Wg, const float* __restrict__ bg,
              const float* __restrict__ W1g, const float* __restrict__ b1g,
              const float* __restrict__ W2g, const float* __restrict__ b2g,
              const float* __restrict__ Wu, const float* __restrict__ bu,
              const float* __restrict__ W1u, const float* __restrict__ b1u,
              const float* __restrict__ W2u, const float* __restrict__ b2u,
              u16* __restrict__ H) {
  __shared__ __align__(16) char smem[RB * BUFB];   // 120 KB
  const int tid = threadIdx.x, lane = tid & 63, wid = tid >> 6;
  const int wm = wid >> 1, wn = wid & 1;
  const int s_ = lane & 15, quad = lane >> 4;
  const int j0 = blockIdx.x * 32;

  // A staging: 16 chunks of [16 rows][64B]; this wave owns chunks 2*wid, 2*wid+1
  // LDS[row][slot] holds global k-chunk slot ^ ((row>>1)&3)  (16B slots, 4/row)
  const int gA = (lane & 3) ^ ((lane >> 3) & 3);
  const int ar0 = 16 * (wid * 2)     + (lane >> 2);
  const int ar1 = 16 * (wid * 2 + 1) + (lane >> 2);
  const u16* srcA0 = X + (size_t)ar0 * KGU + gA * 8;
  const u16* srcA1 = X + (size_t)ar1 * KGU + gA * 8;
  const int dA0 = (wid * 2) * 1024, dA1 = (wid * 2 + 1) * 1024, dB = ABUF + wid * 1024;

  // B staging: 8 chunks of [8 rows][128B]; wave owns chunk wid.
  // LDS[row][slot] holds global 16B-chunk slot ^ (row&7)  (8 slots/row, fp32)
  const int br = 8 * wid + (lane >> 3);           // 0..63: 0-31 gate, 32-63 up
  const int gB = (lane & 7) ^ ((lane >> 3) & 7);
  const float* srcB = ((br < 32) ? (Wg + (size_t)(j0 + br) * KGU)
                                 : (Wu + (size_t)(j0 + br - 32) * KGU)) + gB * 4;

  const int aslot = (quad ^ ((s_ >> 1) & 3)) << 4;
  const int bs0 = ((2 * quad)     ^ (s_ & 7)) << 4;
  const int bs1 = ((2 * quad + 1) ^ (s_ & 7)) << 4;

  f32x4 acc[4][2];
#pragma unroll
  for (int i = 0; i < 4; ++i) { acc[i][0] = (f32x4)0.f; acc[i][1] = (f32x4)0.f; }

  auto stage = [&](int bufb, int kt) {
    gl_lds16(srcA0 + kt, smem + bufb + dA0);
    gl_lds16(srcA1 + kt, smem + bufb + dA1);
    gl_lds16(srcB  + kt, smem + bufb + dB);
  };
  auto compute = [&](const char* base) {
    short8 af[4];
#pragma unroll
    for (int mi = 0; mi < 4; ++mi) {
      int row = wm * 64 + mi * 16 + s_;
      af[mi] = *(const short8*)(base + row * 64 + aslot);
    }
#pragma unroll
    for (int n = 0; n < 2; ++n) {
      int row = n * 32 + wn * 16 + s_;
      const char* bb = base + ABUF + row * 128;
      float4 fa = *(const float4*)(bb + bs0);
      float4 fb = *(const float4*)(bb + bs1);
      short8 bf = mk_bf8(fa, fb);
#pragma unroll
      for (int mi = 0; mi < 4; ++mi)
        acc[mi][n] = __builtin_amdgcn_mfma_f32_16x16x32_bf16(af[mi], bf, acc[mi][n], 0, 0, 0);
    }
  };

  stage(0, 0); stage(BUFB, 32); stage(2 * BUFB, 64);
  int bs_ = 3, bc_ = 0;
#pragma unroll 1
  for (int t = 0; t < 157; ++t) {                 // 160 K-steps total
    stage(bs_ * BUFB, (t + 3) * 32);
    if (++bs_ == RB) bs_ = 0;
    asm volatile("s_waitcnt vmcnt(9)" ::: "memory");
    __builtin_amdgcn_s_barrier();
    __builtin_amdgcn_sched_barrier(0);
    compute(smem + bc_ * BUFB);
    if (++bc_ == RB) bc_ = 0;
  }
  asm volatile("s_waitcnt vmcnt(6)" ::: "memory");
  __builtin_amdgcn_s_barrier();
  __builtin_amdgcn_sched_barrier(0);
  compute(smem + bc_ * BUFB); if (++bc_ == RB) bc_ = 0;
  asm volatile("s_waitcnt vmcnt(3)" ::: "memory");
  __builtin_amdgcn_s_barrier();
  __builtin_amdgcn_sched_barrier(0);
  compute(smem + bc_ * BUFB); if (++bc_ == RB) bc_ = 0;
  asm volatile("s_waitcnt vmcnt(0)" ::: "memory");
  __builtin_amdgcn_s_barrier();
  __builtin_amdgcn_sched_barrier(0);
  compute(smem + bc_ * BUFB);

  // ---- epilogue: per-channel MLP + silu*up ----
  __syncthreads();
  float4* mcg0 = (float4*)smem;
  float*  mcg1 = (float*)(smem + 512);
  float4* mcu0 = (float4*)(smem + 1024);
  float*  mcu1 = (float*)(smem + 1536);
  if (tid < 32) {
    const float* w = W1g + tid * 6;
    mcg0[tid] = make_float4(w[0] + w[2] + w[4], w[1] + w[3] + w[5], b1g[tid], W2g[tid]);
    mcg1[tid] = W2g[32 + tid];
    const float* w2 = W1u + tid * 6;
    mcu0[tid] = make_float4(w2[0] + w2[2] + w2[4], w2[1] + w2[3] + w2[5], b1u[tid], W2u[tid]);
    mcu1[tid] = W2u[32 + tid];
  }
  __syncthreads();
  const float b2g0 = b2g[0], b2g1v = b2g[1], b2u0 = b2u[0], b2u1v = b2u[1];
  const int j = j0 + wn * 16 + s_;
  const float bpg = bg[j], bpu = bu[j];
#pragma unroll
  for (int mi = 0; mi < 4; ++mi) {
    float pg[4], pu[4], hv[8];
#pragma unroll
    for (int e = 0; e < 4; ++e) {
      pg[e] = acc[mi][0][e] + bpg;
      pu[e] = acc[mi][1][e] + bpu;
    }
    qrun4x2(pg, pu, mcg0, mcg1, b2g0, b2g1v, mcu0, mcu1, b2u0, b2u1v, hv);
    const int mrow = wm * 64 + mi * 16 + (quad << 2);
#pragma unroll
    for (int e = 0; e < 4; ++e)
      *(uint32_t*)&H[(size_t)(mrow + e) * HCOL + 2 * j] = pk2(hv[2 * e], hv[2 * e + 1]);
  }
}

// ---------------- kernel 2: down GEMM (split-K) -> fp32 partials ----------------
// 512 thr (8 waves: wm 0..3 x wn 0..1), tile M=256 x N=64, BK=32, same ring.
__global__ __launch_bounds__(512, 2)
void k_down(const u16* __restrict__ Hb, const float* __restrict__ Wd, float* __restrict__ P) {
  __shared__ __align__(16) char smem[RB * BUFB];
  const int tid = threadIdx.x, lane = tid & 63, wid = tid >> 6;
  const int wm = wid >> 1, wn = wid & 1;
  const int s_ = lane & 15, quad = lane >> 4;
  const int n0 = blockIdx.x * 64;
  const int kc = blockIdx.y * KCH;

  const int gA = (lane & 3) ^ ((lane >> 3) & 3);
  const int ar0 = 16 * (wid * 2)     + (lane >> 2);
  const int ar1 = 16 * (wid * 2 + 1) + (lane >> 2);
  const u16* srcA0 = Hb + (size_t)ar0 * KD + kc + gA * 8;
  const u16* srcA1 = Hb + (size_t)ar1 * KD + kc + gA * 8;
  const int dA0 = (wid * 2) * 1024, dA1 = (wid * 2 + 1) * 1024, dB = ABUF + wid * 1024;

  const int br = 8 * wid + (lane >> 3);
  const int gB = (lane & 7) ^ ((lane >> 3) & 7);
  const float* srcB = Wd + (size_t)(n0 + br) * KD + kc + gB * 4;

  const int aslot = (quad ^ ((s_ >> 1) & 3)) << 4;
  const int bs0 = ((2 * quad)     ^ (s_ & 7)) << 4;
  const int bs1 = ((2 * quad + 1) ^ (s_ & 7)) << 4;

  f32x4 acc[4][2];
#pragma unroll
  for (int i = 0; i < 4; ++i) { acc[i][0] = (f32x4)0.f; acc[i][1] = (f32x4)0.f; }

  auto stage = [&](int bufb, int kt) {
    gl_lds16(srcA0 + kt, smem + bufb + dA0);
    gl_lds16(srcA1 + kt, smem + bufb + dA1);
    gl_lds16(srcB  + kt, smem + bufb + dB);
  };
  auto compute = [&](const char* base) {
    short8 af[4];
#pragma unroll
    for (int mi = 0; mi < 4; ++mi) {
      int row = wm * 64 + mi * 16 + s_;
      af[mi] = *(const short8*)(base + row * 64 + aslot);
    }
#pragma unroll
    for (int nI = 0; nI < 2; ++nI) {
      int row = wn * 32 + nI * 16 + s_;
      const char* bb = base + ABUF + row * 128;
      float4 fa = *(const float4*)(bb + bs0);
      float4 fb = *(const float4*)(bb + bs1);
      short8 bf = mk_bf8(fa, fb);
#pragma unroll
      for (int mi = 0; mi < 4; ++mi)
        acc[mi][nI] = __builtin_amdgcn_mfma_f32_16x16x32_bf16(af[mi], bf, acc[mi][nI], 0, 0, 0);
    }
  };

  stage(0, 0); stage(BUFB, 32); stage(2 * BUFB, 64);
  int bs_ = 3, bc_ = 0;
#pragma unroll 1
  for (int t = 0; t < 51; ++t) {                  // 54 K-steps total
    stage(bs_ * BUFB, (t + 3) * 32);
    if (++bs_ == RB) bs_ = 0;
    asm volatile("s_waitcnt vmcnt(9)" ::: "memory");
    __builtin_amdgcn_s_barrier();
    __builtin_amdgcn_sched_barrier(0);
    compute(smem + bc_ * BUFB);
    if (++bc_ == RB) bc_ = 0;
  }
  asm volatile("s_waitcnt vmcnt(6)" ::: "memory");
  __builtin_amdgcn_s_barrier();
  __builtin_amdgcn_sched_barrier(0);
  compute(smem + bc_ * BUFB); if (++bc_ == RB) bc_ = 0;
  asm volatile("s_waitcnt vmcnt(3)" ::: "memory");
  __builtin_amdgcn_s_barrier();
  __builtin_amdgcn_sched_barrier(0);
  compute(smem + bc_ * BUFB); if (++bc_ == RB) bc_ = 0;
  asm volatile("s_waitcnt vmcnt(0)" ::: "memory");
  __builtin_amdgcn_s_barrier();
  __builtin_amdgcn_sched_barrier(0);
  compute(smem + bc_ * BUFB);

  const size_t pb = (size_t)blockIdx.y * PELEMS;
#pragma unroll
  for (int mi = 0; mi < 4; ++mi) {
    int mrow = wm * 64 + mi * 16 + (quad << 2);
#pragma unroll
    for (int nI = 0; nI < 2; ++nI) {
      int n = n0 + wn * 32 + nI * 16 + s_;
#pragma unroll
      for (int e = 0; e < 4; ++e)
        P[pb + (size_t)(mrow + e) * NPD + n] = acc[mi][nI][e];
    }
  }
}

// ---------------- kernel 3: reduce partials + QRUN-d epilogue -> out fp32 ----------------
__global__ __launch_bounds__(256) void k_fin(const float* __restrict__ P, const float* __restrict__ bd,
    const float* __restrict__ W1d, const float* __restrict__ b1d, const float* __restrict__ W2d,
    const float* __restrict__ b2d, float* __restrict__ out) {
  __shared__ float4 mc0[32];
  __shared__ float mc1[32];
  const int tid = threadIdx.x;
  if (tid < 32) {
    const float* w = W1d + tid * 6;
    mc0[tid] = make_float4(w[0] + w[2] + w[4], w[1] + w[3] + w[5], b1d[tid], W2d[tid]);
    mc1[tid] = W2d[32 + tid];
  }
  __syncthreads();
  const int idx = blockIdx.x * 256 + tid;          // < 655360
  const int m = idx / NPD, j = idx - m * NPD;
  float p = bd[j];
#pragma unroll
  for (int sk = 0; sk < SPLITK; ++sk) p += P[(size_t)sk * PELEMS + idx];
  float s = __sinf(p), c = __cosf(p);
  float o0 = b2d[0], o1 = b2d[1];
#pragma unroll 4
  for (int mm = 0; mm < 32; ++mm) {
    float4 k = mc0[mm];
    float hh = fmaxf(fmaf(s, k.x, fmaf(c, k.y, k.z)), 0.f);
    o0 = fmaf(hh, k.w, o0);
    o1 = fmaf(hh, mc1[mm], o1);
  }
  *(float2*)&out[(size_t)m * 5120 + 2 * j] = make_float2(o0, o1);
}

extern "C" void kernel_launch(void* const* d_in, const int* in_sizes, int n_in,
                              void* d_out, int out_size, void* d_ws, size_t ws_size,
                              hipStream_t stream) {
  const float* x   = (const float*)d_in[0];
  const float* Wg  = (const float*)d_in[1];
  const float* bg  = (const float*)d_in[2];
  const float* W1g = (const float*)d_in[3];
  const float* b1g = (const float*)d_in[4];
  const float* W2g = (const float*)d_in[5];
  const float* b2g = (const float*)d_in[6];
  const float* Wu  = (const float*)d_in[7];
  const float* bu  = (const float*)d_in[8];
  const float* W1u = (const float*)d_in[9];
  const float* b1u = (const float*)d_in[10];
  const float* W2u = (const float*)d_in[11];
  const float* b2u = (const float*)d_in[12];
  const float* Wd  = (const float*)d_in[13];
  const float* bd  = (const float*)d_in[14];
  const float* W1d = (const float*)d_in[15];
  const float* b1d = (const float*)d_in[16];
  const float* W2d = (const float*)d_in[17];
  const float* b2d = (const float*)d_in[18];
  char* ws = (char*)d_ws;
  u16*  xb = (u16*)ws;                    // 2,621,440 B
  u16*  hb = (u16*)(ws + 2621440);        // 14,155,776 B
  float* P = (float*)(ws + 16777216);     // 41,943,040 B
  if (ws_size < 58720256u) return;

  k_cvt<<<dim3(640), dim3(256), 0, stream>>>(x, xb);
  k_gateup<<<dim3(432), dim3(512), 0, stream>>>(xb, Wg, bg, W1g, b1g, W2g, b2g,
                                                Wu, bu, W1u, b1u, W2u, b2u, hb);
  k_down<<<dim3(40, SPLITK), dim3(512), 0, stream>>>(hb, Wd, P);
  k_fin<<<dim3(2560), dim3(256), 0, stream>>>(P, bd, W1d, b1d, W2d, b2d, (float*)d_out);
}

// Round 3
// 429.459 us; speedup vs baseline: 1.0804x; 1.0804x over previous
//
#include <hip/hip_runtime.h>
#include <stdint.h>

typedef unsigned short u16;
typedef __attribute__((ext_vector_type(8))) short short8;
typedef __attribute__((ext_vector_type(4))) float f32x4;

#define KGU  5120
#define HCOL 27648
#define NPD  2560
#define KD   27648
#define SPLITD 12
#define KCHD 2304            // 27648/12
#define PEL (256*2560)

__device__ __forceinline__ void gl_lds16(const void* gp, void* lp) {
  __builtin_amdgcn_global_load_lds((const __attribute__((address_space(1))) uint32_t*)gp,
                                   (__attribute__((address_space(3))) uint32_t*)lp, 16, 0, 0);
}
__device__ __forceinline__ uint32_t f2bf(float x) {
  uint32_t b = __float_as_uint(x);
  return (b + 0x7fffu + ((b >> 16) & 1u)) >> 16;
}
__device__ __forceinline__ uint32_t pk2(float lo, float hi) { return f2bf(lo) | (f2bf(hi) << 16); }
__device__ __forceinline__ float silu(float x) {
  return x * __builtin_amdgcn_rcpf(1.f + __expf(-x));
}
__device__ __forceinline__ short8 mk_bf8(const float4& a, const float4& b) {
  union { uint32_t u[4]; short8 s; } cv;
  cv.u[0] = pk2(a.x, a.y); cv.u[1] = pk2(a.z, a.w);
  cv.u[2] = pk2(b.x, b.y); cv.u[3] = pk2(b.z, b.w);
  return cv.s;
}

// ---------------- kernel 0: x fp32 -> bf16 ----------------
__global__ __launch_bounds__(256) void k_cvt(const float* __restrict__ X, u16* __restrict__ Xb) {
  int i = (blockIdx.x * 256 + threadIdx.x) * 8;
  float4 a = *(const float4*)(X + i);
  float4 b = *(const float4*)(X + i + 4);
  uint4 v;
  v.x = pk2(a.x, a.y); v.y = pk2(a.z, a.w); v.z = pk2(b.x, b.y); v.w = pk2(b.z, b.w);
  *(uint4*)(Xb + i) = v;
}

// ---------------- kernel 1: gate+up full-K GEMM + fused QRUN/silu epilogue ----------------
// BM=128 tokens x 256 cols (gate/up channel-interleaved), BK=64, full K=5120.
// 512 thr (8 waves 2M x 4N, per-wave 64x64). grid (108 j-tiles, 2 m-halves) = 216 blocks.
// LDS/buf: A 16KB + B 32KB = 48KB; 2 bufs + 2KB consts.
__global__ __launch_bounds__(512, 2)
void k_gu(const u16* __restrict__ X,
          const float* __restrict__ Wg, const float* __restrict__ bg,
          const float* __restrict__ W1g, const float* __restrict__ b1g,
          const float* __restrict__ W2g, const float* __restrict__ b2g,
          const float* __restrict__ Wu, const float* __restrict__ bu,
          const float* __restrict__ W1u, const float* __restrict__ b1u,
          const float* __restrict__ W2u, const float* __restrict__ b2u,
          u16* __restrict__ H) {
  __shared__ __align__(16) char smem[2 * 49152 + 2048];
  const int tid = threadIdx.x, lane = tid & 63, wid = tid >> 6;
  const int wm = wid >> 2, wn = wid & 3;
  const int s_ = lane & 15, q = lane >> 4;
  const int j0 = blockIdx.x * 128;
  const int m0 = blockIdx.y * 128;

  float4* mc4 = (float4*)(smem + 98304);         // [2][32] {A,B,b1,W2r0}
  float*  mc1 = (float*)(smem + 98304 + 1024);   // [2][32] W2r1
  if (tid < 64) {
    int sel = tid >> 5, m = tid & 31;
    const float* w1 = (sel ? W1u : W1g) + m * 6;
    const float* b1 = sel ? b1u : b1g;
    const float* w2 = sel ? W2u : W2g;
    mc4[sel * 32 + m] = make_float4(w1[0] + w1[2] + w1[4], w1[1] + w1[3] + w1[5], b1[m], w2[m]);
    mc1[sel * 32 + m] = w2[32 + m];
  }

  // A staging: 16 x 1KB chunks (8 rows x 128B each); wave owns chunks wid*2, wid*2+1.
  // LDS[row][s] = Aglob[row][s ^ (row&7)] via pre-swizzled source.
  const int arow = lane >> 3;
  const int aslot = (lane & 7) ^ arow;
  const u16* srcA = X + (size_t)(m0 + wid * 16 + arow) * KGU + aslot * 8;

  // B staging: LDS row r: even -> Wg[j0+(r>>1)], odd -> Wu[j0+(r>>1)]. 2 thr/row.
  const int brr = tid >> 1, bkh = tid & 1;
  const int bj = j0 + (brr >> 1);
  const float* srcB = ((brr & 1) ? Wu : Wg) + (size_t)bj * KGU + bkh * 32;
  int bws[4];
#pragma unroll
  for (int j4 = 0; j4 < 4; ++j4)
    bws[j4] = 16384 + brr * 128 + ((((bkh << 2) | j4) ^ (brr & 7)) << 4);

  f32x4 acc[4][4];
#pragma unroll
  for (int i = 0; i < 4; ++i)
#pragma unroll
    for (int j = 0; j < 4; ++j) acc[i][j] = (f32x4)0.f;
  float4 breg[8];

  auto issueB = [&](int kt) {
#pragma unroll
    for (int i = 0; i < 8; ++i) breg[i] = *(const float4*)(srcB + kt + i * 4);
  };
  auto issueA = [&](int buf, int kt) {
    gl_lds16(srcA + kt, smem + buf + wid * 2048);
    gl_lds16(srcA + 8 * KGU + kt, smem + buf + wid * 2048 + 1024);
  };
  auto writeB = [&](int buf) {
#pragma unroll
    for (int j4 = 0; j4 < 4; ++j4)
      *(short8*)(smem + buf + bws[j4]) = mk_bf8(breg[2 * j4], breg[2 * j4 + 1]);
  };
  auto compute = [&](const char* base) {
#pragma unroll
    for (int kk = 0; kk < 2; ++kk) {
      short8 af[4], bf[4];
#pragma unroll
      for (int mi = 0; mi < 4; ++mi) {
        int row = wm * 64 + mi * 16 + s_;
        af[mi] = *(const short8*)(base + row * 128 + ((((kk << 2) | q) ^ (row & 7)) << 4));
      }
#pragma unroll
      for (int ni = 0; ni < 4; ++ni) {
        int row = wn * 64 + ni * 16 + s_;
        bf[ni] = *(const short8*)(base + 16384 + row * 128 + ((((kk << 2) | q) ^ (row & 7)) << 4));
      }
      __builtin_amdgcn_s_setprio(1);
#pragma unroll
      for (int mi = 0; mi < 4; ++mi)
#pragma unroll
        for (int ni = 0; ni < 4; ++ni)
          acc[mi][ni] = __builtin_amdgcn_mfma_f32_16x16x32_bf16(af[mi], bf[ni], acc[mi][ni], 0, 0, 0);
      __builtin_amdgcn_s_setprio(0);
    }
  };

  // prologue: tile 0
  issueB(0);
  __builtin_amdgcn_sched_barrier(0);
  issueA(0, 0);
  __builtin_amdgcn_sched_barrier(0);
  writeB(0);
  asm volatile("s_waitcnt lgkmcnt(0)" ::: "memory");
  __builtin_amdgcn_sched_barrier(0);
  __builtin_amdgcn_s_barrier();
  int cur = 0;
#pragma unroll 1
  for (int t = 0; t < 79; ++t) {                 // 80 K-tiles
    const int kt = (t + 1) * 64;
    const int bo = cur * 49152, bn = 49152 - bo;
    issueB(kt);
    __builtin_amdgcn_sched_barrier(0);
    issueA(bn, kt);
    asm volatile("s_waitcnt vmcnt(10)" ::: "memory");
    __builtin_amdgcn_sched_barrier(0);
    compute(smem + bo);
    __builtin_amdgcn_sched_barrier(0);
    writeB(bn);
    asm volatile("s_waitcnt lgkmcnt(0)" ::: "memory");
    __builtin_amdgcn_sched_barrier(0);
    __builtin_amdgcn_s_barrier();
    cur ^= 1;
  }
  asm volatile("s_waitcnt vmcnt(0)" ::: "memory");
  __builtin_amdgcn_sched_barrier(0);
  compute(smem + cur * 49152);

  // ---- fused epilogue: per-lane qrun (gate on even lanes, up on odd), shfl pair, silu*up ----
  const int sel = lane & 1;
  const float b2v0 = sel ? b2u[0] : b2g[0];
  const float b2v1 = sel ? b2u[1] : b2g[1];
  const float4* mcs = mc4 + sel * 32;
  const float*  mcw = mc1 + sel * 32;
#pragma unroll
  for (int ni = 0; ni < 4; ++ni) {
    const int c = wn * 64 + ni * 16 + s_;
    const int j = j0 + (c >> 1);
    const float bp = sel ? bu[j] : bg[j];
#pragma unroll
    for (int mi = 0; mi < 4; ++mi) {
      float sv[4], cv[4], o0[4], o1[4];
#pragma unroll
      for (int e = 0; e < 4; ++e) {
        float p = acc[mi][ni][e] + bp;
        sv[e] = __sinf(p); cv[e] = __cosf(p);
        o0[e] = b2v0; o1[e] = b2v1;
      }
#pragma unroll 4
      for (int m = 0; m < 32; ++m) {
        float4 k4 = mcs[m]; float w2b = mcw[m];
#pragma unroll
        for (int e = 0; e < 4; ++e) {
          float hh = fmaxf(fmaf(sv[e], k4.x, fmaf(cv[e], k4.y, k4.z)), 0.f);
          o0[e] = fmaf(hh, k4.w, o0[e]);
          o1[e] = fmaf(hh, w2b, o1[e]);
        }
      }
#pragma unroll
      for (int e = 0; e < 4; ++e) {
        float t0 = __shfl_xor(o0[e], 1);
        float t1 = __shfl_xor(o1[e], 1);
        float g0 = sel ? t0 : o0[e];
        float u0 = sel ? o0[e] : t0;
        float g1 = sel ? t1 : o1[e];
        float u1 = sel ? o1[e] : t1;
        float h0 = silu(g0) * u0, h1 = silu(g1) * u1;
        if (!sel) {
          const int row = m0 + wm * 64 + mi * 16 + q * 4 + e;
          *(uint32_t*)&H[(size_t)row * HCOL + 2 * j] = pk2(h0, h1);
        }
      }
    }
  }
}

// ---------------- kernel 2: down GEMM, BM=256 x BN=128, splitK=12 -> fp32 partials ----------------
// 512 thr (8 waves 2M x 4N, per-wave 128x32). grid (20, 12). LDS: A 32KB + B 16KB, 2 bufs = 96KB.
__global__ __launch_bounds__(512, 2)
void k_down(const u16* __restrict__ Hb, const float* __restrict__ Wd, float* __restrict__ P2) {
  __shared__ __align__(16) char smem[2 * 49152];
  const int tid = threadIdx.x, lane = tid & 63, wid = tid >> 6;
  const int wm = wid >> 2, wn = wid & 3;
  const int s_ = lane & 15, q = lane >> 4;
  const int n0 = blockIdx.x * 128;
  const int kc = blockIdx.y * KCHD;

  const int arow = lane >> 3;
  const int aslot = (lane & 7) ^ arow;
  const u16* srcA = Hb + (size_t)(wid * 32 + arow) * KD + kc + aslot * 8;

  const int brr = tid >> 2, tq = tid & 3;
  const float* srcB = Wd + (size_t)(n0 + brr) * KD + kc + tq * 16;
  const int bw0 = 32768 + brr * 128 + ((((tq << 1) | 0) ^ (brr & 7)) << 4);
  const int bw1 = 32768 + brr * 128 + ((((tq << 1) | 1) ^ (brr & 7)) << 4);

  f32x4 acc[8][2];
#pragma unroll
  for (int i = 0; i < 8; ++i) { acc[i][0] = (f32x4)0.f; acc[i][1] = (f32x4)0.f; }
  float4 breg[4];

  auto issueB = [&](int kt) {
#pragma unroll
    for (int i = 0; i < 4; ++i) breg[i] = *(const float4*)(srcB + kt + i * 4);
  };
  auto issueA = [&](int buf, int kt) {
#pragma unroll
    for (int i = 0; i < 4; ++i)
      gl_lds16(srcA + (size_t)i * 8 * KD + kt, smem + buf + wid * 4096 + i * 1024);
  };
  auto writeB = [&](int buf) {
    *(short8*)(smem + buf + bw0) = mk_bf8(breg[0], breg[1]);
    *(short8*)(smem + buf + bw1) = mk_bf8(breg[2], breg[3]);
  };
  auto compute = [&](const char* base) {
#pragma unroll
    for (int kk = 0; kk < 2; ++kk) {
      short8 af[8], bf[2];
#pragma unroll
      for (int mi = 0; mi < 8; ++mi) {
        int row = wm * 128 + mi * 16 + s_;
        af[mi] = *(const short8*)(base + row * 128 + ((((kk << 2) | q) ^ (row & 7)) << 4));
      }
#pragma unroll
      for (int ni = 0; ni < 2; ++ni) {
        int row = wn * 32 + ni * 16 + s_;
        bf[ni] = *(const short8*)(base + 32768 + row * 128 + ((((kk << 2) | q) ^ (row & 7)) << 4));
      }
      __builtin_amdgcn_s_setprio(1);
#pragma unroll
      for (int mi = 0; mi < 8; ++mi)
#pragma unroll
        for (int ni = 0; ni < 2; ++ni)
          acc[mi][ni] = __builtin_amdgcn_mfma_f32_16x16x32_bf16(af[mi], bf[ni], acc[mi][ni], 0, 0, 0);
      __builtin_amdgcn_s_setprio(0);
    }
  };

  issueB(0);
  __builtin_amdgcn_sched_barrier(0);
  issueA(0, 0);
  __builtin_amdgcn_sched_barrier(0);
  writeB(0);
  asm volatile("s_waitcnt lgkmcnt(0)" ::: "memory");
  __builtin_amdgcn_sched_barrier(0);
  __builtin_amdgcn_s_barrier();
  int cur = 0;
#pragma unroll 1
  for (int t = 0; t < 35; ++t) {                  // 36 K-tiles
    const int kt = (t + 1) * 64;
    const int bo = cur * 49152, bn = 49152 - bo;
    issueB(kt);
    __builtin_amdgcn_sched_barrier(0);
    issueA(bn, kt);
    asm volatile("s_waitcnt vmcnt(8)" ::: "memory");
    __builtin_amdgcn_sched_barrier(0);
    compute(smem + bo);
    __builtin_amdgcn_sched_barrier(0);
    writeB(bn);
    asm volatile("s_waitcnt lgkmcnt(0)" ::: "memory");
    __builtin_amdgcn_sched_barrier(0);
    __builtin_amdgcn_s_barrier();
    cur ^= 1;
  }
  asm volatile("s_waitcnt vmcnt(0)" ::: "memory");
  __builtin_amdgcn_sched_barrier(0);
  compute(smem + cur * 49152);

  const size_t pb = (size_t)blockIdx.y * PEL;
#pragma unroll
  for (int mi = 0; mi < 8; ++mi) {
    int mrow = wm * 128 + mi * 16 + (q << 2);
#pragma unroll
    for (int ni = 0; ni < 2; ++ni) {
      int n = n0 + wn * 32 + ni * 16 + s_;
#pragma unroll
      for (int e = 0; e < 4; ++e)
        P2[pb + (size_t)(mrow + e) * NPD + n] = acc[mi][ni][e];
    }
  }
}

// ---------------- kernel 3: reduce partials + QRUN-d epilogue -> out fp32 ----------------
__global__ __launch_bounds__(256) void k_fin(const float* __restrict__ P2, const float* __restrict__ bd,
    const float* __restrict__ W1d, const float* __restrict__ b1d, const float* __restrict__ W2d,
    const float* __restrict__ b2d, float* __restrict__ out) {
  __shared__ float4 mc0[32];
  __shared__ float mc1[32];
  const int tid = threadIdx.x;
  if (tid < 32) {
    const float* w = W1d + tid * 6;
    mc0[tid] = make_float4(w[0] + w[2] + w[4], w[1] + w[3] + w[5], b1d[tid], W2d[tid]);
    mc1[tid] = W2d[32 + tid];
  }
  __syncthreads();
  const int idx = blockIdx.x * 256 + tid;          // < 655360
  const int m = idx / NPD, j = idx - m * NPD;
  float p = bd[j];
#pragma unroll
  for (int sk = 0; sk < SPLITD; ++sk) p += P2[(size_t)sk * PEL + idx];
  float s = __sinf(p), c = __cosf(p);
  float o0 = b2d[0], o1 = b2d[1];
#pragma unroll 4
  for (int mm = 0; mm < 32; ++mm) {
    float4 k = mc0[mm];
    float hh = fmaxf(fmaf(s, k.x, fmaf(c, k.y, k.z)), 0.f);
    o0 = fmaf(hh, k.w, o0);
    o1 = fmaf(hh, mc1[mm], o1);
  }
  *(float2*)&out[(size_t)m * 5120 + 2 * j] = make_float2(o0, o1);
}

extern "C" void kernel_launch(void* const* d_in, const int* in_sizes, int n_in,
                              void* d_out, int out_size, void* d_ws, size_t ws_size,
                              hipStream_t stream) {
  const float* x   = (const float*)d_in[0];
  const float* Wg  = (const float*)d_in[1];
  const float* bg  = (const float*)d_in[2];
  const float* W1g = (const float*)d_in[3];
  const float* b1g = (const float*)d_in[4];
  const float* W2g = (const float*)d_in[5];
  const float* b2g = (const float*)d_in[6];
  const float* Wu  = (const float*)d_in[7];
  const float* bu  = (const float*)d_in[8];
  const float* W1u = (const float*)d_in[9];
  const float* b1u = (const float*)d_in[10];
  const float* W2u = (const float*)d_in[11];
  const float* b2u = (const float*)d_in[12];
  const float* Wd  = (const float*)d_in[13];
  const float* bd  = (const float*)d_in[14];
  const float* W1d = (const float*)d_in[15];
  const float* b1d = (const float*)d_in[16];
  const float* W2d = (const float*)d_in[17];
  const float* b2d = (const float*)d_in[18];
  char* ws = (char*)d_ws;
  u16*  xb = (u16*)ws;                    // 2,621,440 B
  u16*  hb = (u16*)(ws + 2621440);        // 14,155,776 B  (ends 16,777,216)
  float* P2 = (float*)(ws + 16777216);    // 12 x 655360 x 4 = 31,457,280 B
  if (ws_size < 48234496u) return;

  k_cvt<<<dim3(640), dim3(256), 0, stream>>>(x, xb);
  k_gu<<<dim3(108, 2), dim3(512), 0, stream>>>(xb, Wg, bg, W1g, b1g, W2g, b2g,
                                               Wu, bu, W1u, b1u, W2u, b2u, hb);
  k_down<<<dim3(20, SPLITD), dim3(512), 0, stream>>>(hb, Wd, P2);
  k_fin<<<dim3(2560), dim3(256), 0, stream>>>(P2, bd, W1d, b1d, W2d, b2d, (float*)d_out);
}

// Round 4
// 370.322 us; speedup vs baseline: 1.2529x; 1.1597x over previous
//
#include <hip/hip_runtime.h>
#include <stdint.h>

typedef unsigned short u16;
typedef __attribute__((ext_vector_type(8))) short short8;
typedef __attribute__((ext_vector_type(4))) float f32x4;

#define KGU  5120
#define HCOL 27648
#define NPD  2560
#define KD   27648
#define SPLITD 12
#define KCHD 2304            // 27648/12
#define PEL (256*2560)

#define RB4   4
#define ABYT  16384          // A: 256 rows x 32 k bf16
#define BBYT  16384          // B: 128 rows x 32 k fp32
#define BUFB  32768

__device__ __forceinline__ void gl_lds16(const void* gp, void* lp) {
  __builtin_amdgcn_global_load_lds((const __attribute__((address_space(1))) uint32_t*)gp,
                                   (__attribute__((address_space(3))) uint32_t*)lp, 16, 0, 0);
}
__device__ __forceinline__ void gl_lds16nt(const void* gp, void* lp) {   // NT hint for streams
  __builtin_amdgcn_global_load_lds((const __attribute__((address_space(1))) uint32_t*)gp,
                                   (__attribute__((address_space(3))) uint32_t*)lp, 16, 0, 2);
}
__device__ __forceinline__ uint32_t f2bf(float x) {
  uint32_t b = __float_as_uint(x);
  return (b + 0x7fffu + ((b >> 16) & 1u)) >> 16;
}
__device__ __forceinline__ uint32_t pk2(float lo, float hi) { return f2bf(lo) | (f2bf(hi) << 16); }
__device__ __forceinline__ float silu(float x) {
  return x * __builtin_amdgcn_rcpf(1.f + __expf(-x));
}
__device__ __forceinline__ short8 mk_bf8(const float4& a, const float4& b) {
  union { uint32_t u[4]; short8 s; } cv;
  cv.u[0] = pk2(a.x, a.y); cv.u[1] = pk2(a.z, a.w);
  cv.u[2] = pk2(b.x, b.y); cv.u[3] = pk2(b.z, b.w);
  return cv.s;
}

// ---------------- kernel 0: x fp32 -> bf16 ----------------
__global__ __launch_bounds__(256) void k_cvt(const float* __restrict__ X, u16* __restrict__ Xb) {
  int i = (blockIdx.x * 256 + threadIdx.x) * 8;
  float4 a = *(const float4*)(X + i);
  float4 b = *(const float4*)(X + i + 4);
  uint4 v;
  v.x = pk2(a.x, a.y); v.y = pk2(a.z, a.w); v.z = pk2(b.x, b.y); v.w = pk2(b.z, b.w);
  *(uint4*)(Xb + i) = v;
}

// ---------------- kernel 1: gate+up GEMM (BM=256 x BN=128 interleaved, BK=32, full K) ----------------
// 512 thr, 8 waves (4M x 2N), per-wave 64x64. grid 216. LDS: 4-ring x 32KB + consts.
// A LDS: [chunk=row>>4][row&15][q] 16B units; B LDS fp32: [chunk=row>>3][row&7][kc] 16B units.
__global__ __launch_bounds__(512, 1)
void k_gu(const u16* __restrict__ X,
          const float* __restrict__ Wg, const float* __restrict__ bg,
          const float* __restrict__ W1g, const float* __restrict__ b1g,
          const float* __restrict__ W2g, const float* __restrict__ b2g,
          const float* __restrict__ Wu, const float* __restrict__ bu,
          const float* __restrict__ W1u, const float* __restrict__ b1u,
          const float* __restrict__ W2u, const float* __restrict__ b2u,
          u16* __restrict__ H) {
  __shared__ __align__(16) char smem[RB4 * BUFB + 1536];
  const int tid = threadIdx.x, lane = tid & 63, wid = tid >> 6;
  const int wm = wid >> 1, wn = wid & 1;
  const int s_ = lane & 15, quad = lane >> 4;
  const int j0 = blockIdx.x * 64;            // 64 j-pairs = 128 interleaved cols

  // MLP consts
  float4* mc4 = (float4*)(smem + RB4 * BUFB);
  float*  mc1 = (float*)(smem + RB4 * BUFB + 1024);
  if (tid < 64) {
    int sel = tid >> 5, m = tid & 31;
    const float* w1 = (sel ? W1u : W1g) + m * 6;
    const float* b1 = sel ? b1u : b1g;
    const float* w2 = sel ? W2u : W2g;
    mc4[sel * 32 + m] = make_float4(w1[0] + w1[2] + w1[4], w1[1] + w1[3] + w1[5], b1[m], w2[m]);
    mc1[sel * 32 + m] = w2[32 + m];
  }

  // A staging: wave owns chunks 2wid, 2wid+1 (16 rows x 4 k-slots each).
  // lane -> (row = 16c + (lane&15), q = lane>>4); global 16B @ row*KGU + kt + q*8 (u16)
  const u16* srcA0 = X + (size_t)(32 * wid + (lane & 15)) * KGU + (lane >> 4) * 8;
  const u16* srcA1 = srcA0 + 16 * KGU;
  // B staging: wave owns chunks 2wid, 2wid+1 (8 rows x 8 kc each).
  // LDS row r (0..127): even -> Wg[j0+(r>>1)], odd -> Wu[j0+(r>>1)]
  const int jrow = j0 + 8 * wid + ((lane & 7) >> 1);
  const float* srcB0 = ((lane & 1) ? Wu : Wg) + (size_t)jrow * KGU + (lane >> 3) * 4;
  const float* srcB1 = srcB0 + 4 * KGU;
  const int dA0 = (2 * wid) * 1024, dA1 = dA0 + 1024;
  const int dB0 = ABYT + (2 * wid) * 1024, dB1 = dB0 + 1024;

  // reader offsets
  const int aoff0 = wm * 4096 + s_ * 16 + quad * 256;                       // +mi*1024
  const int boff0 = ABYT + wn * 8192 + (s_ >> 3) * 1024 + (s_ & 7) * 16 + quad * 256;  // +ni*2048

  f32x4 acc[4][4];
#pragma unroll
  for (int i = 0; i < 4; ++i)
#pragma unroll
    for (int j = 0; j < 4; ++j) acc[i][j] = (f32x4)0.f;

  auto stage = [&](int bufb, int t) {
    const int kt = t * 32;
    gl_lds16(srcA0 + kt, smem + bufb + dA0);
    gl_lds16(srcA1 + kt, smem + bufb + dA1);
    gl_lds16nt(srcB0 + kt, smem + bufb + dB0);
    gl_lds16nt(srcB1 + kt, smem + bufb + dB1);
  };
  auto compute = [&](int bufb) {
    const char* base = smem + bufb;
    short8 af[4], bf[4];
#pragma unroll
    for (int mi = 0; mi < 4; ++mi)
      af[mi] = *(const short8*)(base + aoff0 + mi * 1024);
#pragma unroll
    for (int ni = 0; ni < 4; ++ni) {
      float4 f0 = *(const float4*)(base + boff0 + ni * 2048);
      float4 f1 = *(const float4*)(base + boff0 + ni * 2048 + 128);
      bf[ni] = mk_bf8(f0, f1);
    }
    __builtin_amdgcn_s_setprio(1);
#pragma unroll
    for (int mi = 0; mi < 4; ++mi)
#pragma unroll
      for (int ni = 0; ni < 4; ++ni)
        acc[mi][ni] = __builtin_amdgcn_mfma_f32_16x16x32_bf16(af[mi], bf[ni], acc[mi][ni], 0, 0, 0);
    __builtin_amdgcn_s_setprio(0);
  };

  stage(0, 0); stage(BUFB, 1);
#pragma unroll 1
  for (int t = 0; t < 158; ++t) {            // 160 K-steps
    stage(((t + 2) & 3) * BUFB, t + 2);
    asm volatile("s_waitcnt vmcnt(8)" ::: "memory");
    __builtin_amdgcn_s_barrier();
    __builtin_amdgcn_sched_barrier(0);
    compute((t & 3) * BUFB);
  }
  asm volatile("s_waitcnt vmcnt(4)" ::: "memory");
  __builtin_amdgcn_s_barrier();
  __builtin_amdgcn_sched_barrier(0);
  compute((158 & 3) * BUFB);
  asm volatile("s_waitcnt vmcnt(0)" ::: "memory");
  __builtin_amdgcn_s_barrier();
  __builtin_amdgcn_sched_barrier(0);
  compute((159 & 3) * BUFB);

  // ---- fused epilogue: qrun per lane (gate even / up odd), shfl pair, silu*up ----
  __syncthreads();
  const int sel = lane & 1;
  const float b2v0 = sel ? b2u[0] : b2g[0];
  const float b2v1 = sel ? b2u[1] : b2g[1];
  const float4* mcs = mc4 + sel * 32;
  const float*  mcw = mc1 + sel * 32;
#pragma unroll
  for (int ni = 0; ni < 4; ++ni) {
    const int c = wn * 64 + ni * 16 + s_;
    const int j = j0 + (c >> 1);
    const float bp = sel ? bu[j] : bg[j];
#pragma unroll
    for (int mi = 0; mi < 4; ++mi) {
      float sv[4], cv[4], o0[4], o1[4];
#pragma unroll
      for (int e = 0; e < 4; ++e) {
        float p = acc[mi][ni][e] + bp;
        sv[e] = __sinf(p); cv[e] = __cosf(p);
        o0[e] = b2v0; o1[e] = b2v1;
      }
#pragma unroll 4
      for (int m = 0; m < 32; ++m) {
        float4 k4 = mcs[m]; float w2b = mcw[m];
#pragma unroll
        for (int e = 0; e < 4; ++e) {
          float hh = fmaxf(fmaf(sv[e], k4.x, fmaf(cv[e], k4.y, k4.z)), 0.f);
          o0[e] = fmaf(hh, k4.w, o0[e]);
          o1[e] = fmaf(hh, w2b, o1[e]);
        }
      }
#pragma unroll
      for (int e = 0; e < 4; ++e) {
        float t0 = __shfl_xor(o0[e], 1);
        float t1 = __shfl_xor(o1[e], 1);
        float g0 = sel ? t0 : o0[e];
        float u0 = sel ? o0[e] : t0;
        float g1 = sel ? t1 : o1[e];
        float u1 = sel ? o1[e] : t1;
        float h0 = silu(g0) * u0, h1 = silu(g1) * u1;
        if (!sel) {
          const int row = wm * 64 + mi * 16 + quad * 4 + e;
          *(uint32_t*)&H[(size_t)row * HCOL + 2 * j] = pk2(h0, h1);
        }
      }
    }
  }
}

// ---------------- kernel 2: down GEMM (BM=256 x BN=128, BK=32, splitK=12) ----------------
__global__ __launch_bounds__(512, 1)
void k_down(const u16* __restrict__ Hb, const float* __restrict__ Wd, float* __restrict__ P2) {
  __shared__ __align__(16) char smem[RB4 * BUFB];
  const int tid = threadIdx.x, lane = tid & 63, wid = tid >> 6;
  const int wm = wid >> 1, wn = wid & 1;
  const int s_ = lane & 15, quad = lane >> 4;
  const int n0 = blockIdx.x * 128;
  const int kc = blockIdx.y * KCHD;

  const u16* srcA0 = Hb + (size_t)(32 * wid + (lane & 15)) * KD + kc + (lane >> 4) * 8;
  const u16* srcA1 = srcA0 + 16 * KD;
  const float* srcB0 = Wd + (size_t)(n0 + 16 * wid + (lane & 7)) * KD + kc + (lane >> 3) * 4;
  const float* srcB1 = srcB0 + 8 * KD;
  const int dA0 = (2 * wid) * 1024, dA1 = dA0 + 1024;
  const int dB0 = ABYT + (2 * wid) * 1024, dB1 = dB0 + 1024;

  const int aoff0 = wm * 4096 + s_ * 16 + quad * 256;
  const int boff0 = ABYT + wn * 8192 + (s_ >> 3) * 1024 + (s_ & 7) * 16 + quad * 256;

  f32x4 acc[4][4];
#pragma unroll
  for (int i = 0; i < 4; ++i)
#pragma unroll
    for (int j = 0; j < 4; ++j) acc[i][j] = (f32x4)0.f;

  auto stage = [&](int bufb, int t) {
    const int kt = t * 32;
    gl_lds16(srcA0 + kt, smem + bufb + dA0);
    gl_lds16(srcA1 + kt, smem + bufb + dA1);
    gl_lds16nt(srcB0 + kt, smem + bufb + dB0);
    gl_lds16nt(srcB1 + kt, smem + bufb + dB1);
  };
  auto compute = [&](int bufb) {
    const char* base = smem + bufb;
    short8 af[4], bf[4];
#pragma unroll
    for (int mi = 0; mi < 4; ++mi)
      af[mi] = *(const short8*)(base + aoff0 + mi * 1024);
#pragma unroll
    for (int ni = 0; ni < 4; ++ni) {
      float4 f0 = *(const float4*)(base + boff0 + ni * 2048);
      float4 f1 = *(const float4*)(base + boff0 + ni * 2048 + 128);
      bf[ni] = mk_bf8(f0, f1);
    }
    __builtin_amdgcn_s_setprio(1);
#pragma unroll
    for (int mi = 0; mi < 4; ++mi)
#pragma unroll
      for (int ni = 0; ni < 4; ++ni)
        acc[mi][ni] = __builtin_amdgcn_mfma_f32_16x16x32_bf16(af[mi], bf[ni], acc[mi][ni], 0, 0, 0);
    __builtin_amdgcn_s_setprio(0);
  };

  stage(0, 0); stage(BUFB, 1);
#pragma unroll 1
  for (int t = 0; t < 70; ++t) {             // 72 K-steps
    stage(((t + 2) & 3) * BUFB, t + 2);
    asm volatile("s_waitcnt vmcnt(8)" ::: "memory");
    __builtin_amdgcn_s_barrier();
    __builtin_amdgcn_sched_barrier(0);
    compute((t & 3) * BUFB);
  }
  asm volatile("s_waitcnt vmcnt(4)" ::: "memory");
  __builtin_amdgcn_s_barrier();
  __builtin_amdgcn_sched_barrier(0);
  compute((70 & 3) * BUFB);
  asm volatile("s_waitcnt vmcnt(0)" ::: "memory");
  __builtin_amdgcn_s_barrier();
  __builtin_amdgcn_sched_barrier(0);
  compute((71 & 3) * BUFB);

  const size_t pb = (size_t)blockIdx.y * PEL;
#pragma unroll
  for (int mi = 0; mi < 4; ++mi) {
    int mrow = wm * 64 + mi * 16 + (quad << 2);
#pragma unroll
    for (int ni = 0; ni < 4; ++ni) {
      int n = n0 + wn * 64 + ni * 16 + s_;
#pragma unroll
      for (int e = 0; e < 4; ++e)
        P2[pb + (size_t)(mrow + e) * NPD + n] = acc[mi][ni][e];
    }
  }
}

// ---------------- kernel 3: reduce partials + QRUN-d epilogue -> out fp32 ----------------
__global__ __launch_bounds__(256) void k_fin(const float* __restrict__ P2, const float* __restrict__ bd,
    const float* __restrict__ W1d, const float* __restrict__ b1d, const float* __restrict__ W2d,
    const float* __restrict__ b2d, float* __restrict__ out) {
  __shared__ float4 mc0[32];
  __shared__ float mc1[32];
  const int tid = threadIdx.x;
  if (tid < 32) {
    const float* w = W1d + tid * 6;
    mc0[tid] = make_float4(w[0] + w[2] + w[4], w[1] + w[3] + w[5], b1d[tid], W2d[tid]);
    mc1[tid] = W2d[32 + tid];
  }
  __syncthreads();
  const int idx = blockIdx.x * 256 + tid;
  const int m = idx / NPD, j = idx - m * NPD;
  float p = bd[j];
#pragma unroll
  for (int sk = 0; sk < SPLITD; ++sk) p += P2[(size_t)sk * PEL + idx];
  float s = __sinf(p), c = __cosf(p);
  float o0 = b2d[0], o1 = b2d[1];
#pragma unroll 4
  for (int mm = 0; mm < 32; ++mm) {
    float4 k = mc0[mm];
    float hh = fmaxf(fmaf(s, k.x, fmaf(c, k.y, k.z)), 0.f);
    o0 = fmaf(hh, k.w, o0);
    o1 = fmaf(hh, mc1[mm], o1);
  }
  *(float2*)&out[(size_t)m * 5120 + 2 * j] = make_float2(o0, o1);
}

extern "C" void kernel_launch(void* const* d_in, const int* in_sizes, int n_in,
                              void* d_out, int out_size, void* d_ws, size_t ws_size,
                              hipStream_t stream) {
  const float* x   = (const float*)d_in[0];
  const float* Wg  = (const float*)d_in[1];
  const float* bg  = (const float*)d_in[2];
  const float* W1g = (const float*)d_in[3];
  const float* b1g = (const float*)d_in[4];
  const float* W2g = (const float*)d_in[5];
  const float* b2g = (const float*)d_in[6];
  const float* Wu  = (const float*)d_in[7];
  const float* bu  = (const float*)d_in[8];
  const float* W1u = (const float*)d_in[9];
  const float* b1u = (const float*)d_in[10];
  const float* W2u = (const float*)d_in[11];
  const float* b2u = (const float*)d_in[12];
  const float* Wd  = (const float*)d_in[13];
  const float* bd  = (const float*)d_in[14];
  const float* W1d = (const float*)d_in[15];
  const float* b1d = (const float*)d_in[16];
  const float* W2d = (const float*)d_in[17];
  const float* b2d = (const float*)d_in[18];
  char* ws = (char*)d_ws;
  u16*  xb = (u16*)ws;                    // 2,621,440 B
  u16*  hb = (u16*)(ws + 2621440);        // 14,155,776 B (ends 16,777,216)
  float* P2 = (float*)(ws + 16777216);    // 12 x 655360 x 4 = 31,457,280 B
  if (ws_size < 48234496u) return;

  k_cvt<<<dim3(640), dim3(256), 0, stream>>>(x, xb);
  k_gu<<<dim3(216), dim3(512), 0, stream>>>(xb, Wg, bg, W1g, b1g, W2g, b2g,
                                            Wu, bu, W1u, b1u, W2u, b2u, hb);
  k_down<<<dim3(20, SPLITD), dim3(512), 0, stream>>>(hb, Wd, P2);
  k_fin<<<dim3(2560), dim3(256), 0, stream>>>(P2, bd, W1d, b1d, W2d, b2d, (float*)d_out);
}